// Round 8
// baseline (399.206 us; speedup 1.0000x reference)
//
#include <hip/hip_runtime.h>
#include <hip/hip_bf16.h>
#include <math.h>

// Problem constants (fixed shapes)
#define SS   2048   // sequence length
#define EE   2048   // embed dim
#define HH   16     // heads
#define QLAT 1536   // q latent
#define KLAT 512    // kv latent
#define DN   128
#define DR   64
#define DV   128
#define DQ   192    // DN+DR
#define KVD  256    // DN+DV
#define CKVW 576    // KLAT+DR
#define QW   3072   // HH*DQ
#define KVW  4096   // HH*KVD
#define OW   2048   // HH*DV
#define QAC  2112   // QLAT + CKVW (merged a-proj output width)

#define NSEG 4      // key segments (flash-decoding split)
#define PT_STRIDE 72
#define KTSZ (6 * 64 * 32)   // one K-chunk in LDS (ushorts)

typedef __attribute__((ext_vector_type(8))) short short8;
typedef __attribute__((ext_vector_type(4))) float f32x4;

// ---------------- helpers ----------------
__global__ void detect_dtype(const unsigned int* __restrict__ lnw, int* flag) {
    *flag = (lnw[0] == 0x3F803F80u) ? 1 : 0;  // bf16 pair of 1.0 vs fp32 1.0
}

__device__ __forceinline__ float ld_in(const void* p, size_t i, int bf) {
    if (bf) return __bfloat162float(((const __hip_bfloat16*)p)[i]);
    return ((const float*)p)[i];
}

__device__ __forceinline__ ushort f2b(float v) {
    __hip_bfloat16 b = __float2bfloat16(v);
    return *(ushort*)&b;
}
__device__ __forceinline__ float b2f(ushort u) {
    __hip_bfloat16 b = *(__hip_bfloat16*)&u;
    return __bfloat162float(b);
}

// async global->LDS, 16 B per lane; LDS dst must be wave-uniform base + lane*16
__device__ __forceinline__ void async16(const ushort* g, ushort* l) {
    __builtin_amdgcn_global_load_lds(
        (const __attribute__((address_space(1))) void*)g,
        (__attribute__((address_space(3))) void*)l, 16, 0, 0);
}

// ---------------- input convert (x -> bf16) ----------------
__global__ __launch_bounds__(256) void conv_x_bf(
    const void* __restrict__ src, ushort* __restrict__ dst, int n, const int* flag) {
    const int bf = *flag;
    int i = (blockIdx.x * 256 + threadIdx.x) * 4;
    if (i >= n) return;
    ushort4 u;
    u.x = f2b(ld_in(src, i + 0, bf));
    u.y = f2b(ld_in(src, i + 1, bf));
    u.z = f2b(ld_in(src, i + 2, bf));
    u.w = f2b(ld_in(src, i + 3, bf));
    *(ushort4*)(dst + i) = u;
}

// ---------------- batched weight transpose+convert: in[R][C] -> out[C][R] bf16 ----
__global__ __launch_bounds__(256) void transpose5_bf(
    const void* __restrict__ s0, const void* __restrict__ s1,
    const void* __restrict__ s2, const void* __restrict__ s3,
    const void* __restrict__ s4,
    ushort* __restrict__ d0, ushort* __restrict__ d1, ushort* __restrict__ d2,
    ushort* __restrict__ d3, ushort* __restrict__ d4,
    const int* flag) {
    const int z = blockIdx.z;
    const void* in; ushort* out; int R, C;
    switch (z) {
        case 0:  in = s0; out = d0; R = EE;   C = QLAT; break;  // w_q_a
        case 1:  in = s1; out = d1; R = EE;   C = CKVW; break;  // w_kv_a
        case 2:  in = s2; out = d2; R = QLAT; C = QW;   break;  // w_q_b
        case 3:  in = s3; out = d3; R = KLAT; C = KVW;  break;  // w_kv_b
        default: in = s4; out = d4; R = OW;   C = EE;   break;  // w_out
    }
    const int c0 = blockIdx.x * 64, r0 = blockIdx.y * 64;
    if (c0 >= C || r0 >= R) return;
    const int bf = *flag;
    __shared__ ushort t[64][66];
    const int lane = threadIdx.x & 63, grp = threadIdx.x >> 6;
    #pragma unroll
    for (int p = 0; p < 16; ++p) {
        int r = p * 4 + grp;
        t[lane][r] = f2b(ld_in(in, (size_t)(r0 + r) * C + c0 + lane, bf));
    }
    __syncthreads();
    const int ro = (threadIdx.x & 31) * 2, co = threadIdx.x >> 5;
    #pragma unroll
    for (int p = 0; p < 8; ++p) {
        int c = p * 8 + co;
        ushort2 u = *(const ushort2*)&t[c][ro];
        *(ushort2*)&out[(size_t)(c0 + c) * R + r0 + ro] = u;
    }
}

// ---------------- bf16 MFMA GEMM 128x128 body, BK=64 double-buffered --------
__device__ __forceinline__ void gemm128_body(
    const ushort* __restrict__ A, const ushort* __restrict__ Bt,
    void* __restrict__ C, int N, int K, int lda, int ldb, int ldc,
    int cbf, int bm, int bn, ushort* As, ushort* Bs) {
    const int tid = threadIdx.x;
    const int lane = tid & 63, wv = tid >> 6;
    const int wm = (wv & 1) * 64, wn = (wv >> 1) * 64;
    const int ln = lane & 15, quad = lane >> 4;

    f32x4 acc[4][4];
    #pragma unroll
    for (int i = 0; i < 4; ++i)
        #pragma unroll
        for (int j = 0; j < 4; ++j) acc[i][j] = (f32x4){0.f, 0.f, 0.f, 0.f};

    const int srow = tid >> 3;                       // 0..31
    const int spart = ((tid & 7) ^ ((tid >> 3) & 7)) * 8;  // swizzled src 16B part
    const ushort* Ag0 = A + (size_t)(bm + srow) * lda + spart;
    const ushort* Ag1 = Ag0 + (size_t)32 * lda;
    const ushort* Ag2 = Ag0 + (size_t)64 * lda;
    const ushort* Ag3 = Ag0 + (size_t)96 * lda;
    const int br0 = (bn + srow)      < N ? (bn + srow)      : (N - 1);
    const int br1 = (bn + 32 + srow) < N ? (bn + 32 + srow) : (N - 1);
    const int br2 = (bn + 64 + srow) < N ? (bn + 64 + srow) : (N - 1);
    const int br3 = (bn + 96 + srow) < N ? (bn + 96 + srow) : (N - 1);
    const ushort* Bg0 = Bt + (size_t)br0 * ldb + spart;
    const ushort* Bg1 = Bt + (size_t)br1 * ldb + spart;
    const ushort* Bg2 = Bt + (size_t)br2 * ldb + spart;
    const ushort* Bg3 = Bt + (size_t)br3 * ldb + spart;
    const int nsteps = K >> 6;

    // prologue: stage step 0 into buffer 0
    {
        ushort* as = As + tid * 8;
        ushort* bs = Bs + tid * 8;
        async16(Ag0, as);          async16(Ag1, as + 2048);
        async16(Ag2, as + 4096);   async16(Ag3, as + 6144);
        async16(Bg0, bs);          async16(Bg1, bs + 2048);
        async16(Bg2, bs + 4096);   async16(Bg3, bs + 6144);
    }

    int cb = 0;
    for (int c = 0; c < nsteps; ++c) {
        asm volatile("s_waitcnt vmcnt(0)" ::: "memory");
        __builtin_amdgcn_s_barrier();
        asm volatile("" ::: "memory");
        if (c + 1 < nsteps) {
            const int k1 = (c + 1) << 6;
            ushort* as = As + (cb ^ 1) * 8192 + tid * 8;
            ushort* bs = Bs + (cb ^ 1) * 8192 + tid * 8;
            async16(Ag0 + k1, as);          async16(Ag1 + k1, as + 2048);
            async16(Ag2 + k1, as + 4096);   async16(Ag3 + k1, as + 6144);
            async16(Bg0 + k1, bs);          async16(Bg1 + k1, bs + 2048);
            async16(Bg2 + k1, bs + 4096);   async16(Bg3 + k1, bs + 6144);
        }
        const ushort* Ac = As + cb * 8192;
        const ushort* Bc = Bs + cb * 8192;
        #pragma unroll
        for (int ks = 0; ks < 2; ++ks) {
            const int sw = ((ks * 4 + quad) ^ (ln & 7)) * 8;
            short8 af[4], bfr[4];
            #pragma unroll
            for (int t = 0; t < 4; ++t) {
                af[t]  = *(const short8*)&Ac[(wm + t * 16 + ln) * 64 + sw];
                bfr[t] = *(const short8*)&Bc[(wn + t * 16 + ln) * 64 + sw];
            }
            __builtin_amdgcn_s_setprio(1);
            #pragma unroll
            for (int i = 0; i < 4; ++i)
                #pragma unroll
                for (int j = 0; j < 4; ++j)
                    acc[i][j] = __builtin_amdgcn_mfma_f32_16x16x32_bf16(af[i], bfr[j], acc[i][j], 0, 0, 0);
            __builtin_amdgcn_s_setprio(0);
        }
        cb ^= 1;
    }

    #pragma unroll
    for (int i = 0; i < 4; ++i) {
        #pragma unroll
        for (int r = 0; r < 4; ++r) {
            const int m = bm + wm + i * 16 + quad * 4 + r;
            #pragma unroll
            for (int j = 0; j < 4; ++j) {
                const int n = bn + wn + j * 16 + ln;
                if (n < N) {
                    if (cbf) ((ushort*)C)[(size_t)m * ldc + n] = f2b(acc[i][j][r]);
                    else     ((float*)C)[(size_t)m * ldc + n] = acc[i][j][r];
                }
            }
        }
    }
}

// merged q_b + kv_b GEMMs: z selects; 896 useful blocks run concurrently
__global__ __launch_bounds__(256) void gemm_qkv(
    const ushort* __restrict__ qac, const ushort* __restrict__ wqbt,
    const ushort* __restrict__ wkvbt, ushort* __restrict__ qbf_,
    ushort* __restrict__ kvbf_) {
    __shared__ ushort As[2 * 8192];
    __shared__ ushort Bs[2 * 8192];
    if (blockIdx.z == 0) {
        if (blockIdx.x >= QW / 128) return;
        gemm128_body(qac, wqbt, qbf_, QW, QLAT, QAC, QLAT, QW, 1,
                     blockIdx.y * 128, blockIdx.x * 128, As, Bs);
    } else {
        gemm128_body(qac + QLAT, wkvbt, kvbf_, KVW, KLAT, QAC, KLAT, KVW, 1,
                     blockIdx.y * 128, blockIdx.x * 128, As, Bs);
    }
}

// ---------------- bf16 MFMA GEMM 64x128, BK=64 double-buffered --------------
__global__ __launch_bounds__(256) void gemm_bf64(
    const ushort* __restrict__ A, const ushort* __restrict__ Bt,
    void* __restrict__ C, int N, int K, int lda, int ldb, int ldc,
    int cmode, const int* __restrict__ cflag) {
    __shared__ ushort As[2 * 4096];
    __shared__ ushort Bs[2 * 8192];
    const int tid = threadIdx.x;
    const int bm = blockIdx.y * 64, bn = blockIdx.x * 128;
    const int lane = tid & 63, wv = tid >> 6;
    const int wm = (wv & 1) * 32, wn = (wv >> 1) * 64;
    const int ln = lane & 15, quad = lane >> 4;

    int cbf = cmode;
    if (cmode == 2) cbf = *(volatile const int*)cflag;  // before staging loads

    f32x4 acc[2][4];
    #pragma unroll
    for (int i = 0; i < 2; ++i)
        #pragma unroll
        for (int j = 0; j < 4; ++j) acc[i][j] = (f32x4){0.f, 0.f, 0.f, 0.f};

    const int srow = tid >> 3;
    const int spart = ((tid & 7) ^ ((tid >> 3) & 7)) * 8;
    const ushort* Ag0 = A + (size_t)(bm + srow) * lda + spart;
    const ushort* Ag1 = Ag0 + (size_t)32 * lda;
    const int br0 = (bn + srow)      < N ? (bn + srow)      : (N - 1);
    const int br1 = (bn + 32 + srow) < N ? (bn + 32 + srow) : (N - 1);
    const int br2 = (bn + 64 + srow) < N ? (bn + 64 + srow) : (N - 1);
    const int br3 = (bn + 96 + srow) < N ? (bn + 96 + srow) : (N - 1);
    const ushort* Bg0 = Bt + (size_t)br0 * ldb + spart;
    const ushort* Bg1 = Bt + (size_t)br1 * ldb + spart;
    const ushort* Bg2 = Bt + (size_t)br2 * ldb + spart;
    const ushort* Bg3 = Bt + (size_t)br3 * ldb + spart;
    const int nsteps = K >> 6;

    {
        ushort* as = As + tid * 8;
        ushort* bs = Bs + tid * 8;
        async16(Ag0, as);          async16(Ag1, as + 2048);
        async16(Bg0, bs);          async16(Bg1, bs + 2048);
        async16(Bg2, bs + 4096);   async16(Bg3, bs + 6144);
    }

    int cb = 0;
    for (int c = 0; c < nsteps; ++c) {
        asm volatile("s_waitcnt vmcnt(0)" ::: "memory");
        __builtin_amdgcn_s_barrier();
        asm volatile("" ::: "memory");
        if (c + 1 < nsteps) {
            const int k1 = (c + 1) << 6;
            ushort* as = As + (cb ^ 1) * 4096 + tid * 8;
            ushort* bs = Bs + (cb ^ 1) * 8192 + tid * 8;
            async16(Ag0 + k1, as);          async16(Ag1 + k1, as + 2048);
            async16(Bg0 + k1, bs);          async16(Bg1 + k1, bs + 2048);
            async16(Bg2 + k1, bs + 4096);   async16(Bg3 + k1, bs + 6144);
        }
        const ushort* Ac = As + cb * 4096;
        const ushort* Bc = Bs + cb * 8192;
        #pragma unroll
        for (int ks = 0; ks < 2; ++ks) {
            const int sw = ((ks * 4 + quad) ^ (ln & 7)) * 8;
            short8 af[2], bfr[4];
            #pragma unroll
            for (int t = 0; t < 2; ++t)
                af[t] = *(const short8*)&Ac[(wm + t * 16 + ln) * 64 + sw];
            #pragma unroll
            for (int t = 0; t < 4; ++t)
                bfr[t] = *(const short8*)&Bc[(wn + t * 16 + ln) * 64 + sw];
            __builtin_amdgcn_s_setprio(1);
            #pragma unroll
            for (int i = 0; i < 2; ++i)
                #pragma unroll
                for (int j = 0; j < 4; ++j)
                    acc[i][j] = __builtin_amdgcn_mfma_f32_16x16x32_bf16(af[i], bfr[j], acc[i][j], 0, 0, 0);
            __builtin_amdgcn_s_setprio(0);
        }
        cb ^= 1;
    }

    #pragma unroll
    for (int i = 0; i < 2; ++i) {
        #pragma unroll
        for (int r = 0; r < 4; ++r) {
            const int m = bm + wm + i * 16 + quad * 4 + r;
            #pragma unroll
            for (int j = 0; j < 4; ++j) {
                const int n = bn + wn + j * 16 + ln;
                if (n < N) {
                    if (cbf) ((ushort*)C)[(size_t)m * ldc + n] = f2b(acc[i][j][r]);
                    else     ((float*)C)[(size_t)m * ldc + n] = acc[i][j][r];
                }
            }
        }
    }
}

// ---------------- RMSNorm bf16 in-place (fp32 math), both norms fused ------
__global__ __launch_bounds__(256) void rmsnorm2_bf(
    ushort* __restrict__ x, const void* __restrict__ wq,
    const void* __restrict__ wkv, const int* wflag) {
    const int wbf = *wflag;
    const int which = blockIdx.y;
    const int cols = which ? KLAT : QLAT;
    const void* w = which ? wkv : wq;
    ushort* p = x + (size_t)blockIdx.x * QAC + (which ? QLAT : 0);
    float ss = 0.f;
    for (int i = threadIdx.x; i < cols; i += 256) { float v = b2f(p[i]); ss += v * v; }
    #pragma unroll
    for (int off = 32; off; off >>= 1) ss += __shfl_xor(ss, off);
    __shared__ float red[4];
    const int wid = threadIdx.x >> 6, lane = threadIdx.x & 63;
    if (lane == 0) red[wid] = ss;
    __syncthreads();
    const float tot = red[0] + red[1] + red[2] + red[3];
    const float scale = rsqrtf(tot / (float)cols + 1e-6f);
    for (int i = threadIdx.x; i < cols; i += 256)
        p[i] = f2b(b2f(p[i]) * scale * ld_in(w, i, wbf));
}

// ---------------- RoPE table ----------------
__global__ __launch_bounds__(256) void rope_tab(float* __restrict__ tab) {
    int idx = blockIdx.x * 256 + threadIdx.x;   // SS*32
    int s = idx >> 5, i = idx & 31;
    float inv = powf(10000.0f, -(float)i / 32.0f);
    float sv, cv;
    sincosf((float)s * inv, &sv, &cv);
    tab[idx * 2]     = cv;
    tab[idx * 2 + 1] = sv;
}

__device__ __forceinline__ void rope_block(
    const ushort* __restrict__ src, ushort* __restrict__ dst,
    const float* __restrict__ tb) {
    short8 vin[8];
    #pragma unroll
    for (int t = 0; t < 8; ++t) vin[t] = *(const short8*)(src + t * 8);
    short8 lo[4], hi[4];
    #pragma unroll
    for (int t = 0; t < 4; ++t) {
        #pragma unroll
        for (int j = 0; j < 8; ++j) {
            const int i = t * 8 + j;
            float cv = tb[2 * i], sv = tb[2 * i + 1];
            ushort u0 = ((const ushort*)&vin[(2 * i) >> 3])[(2 * i) & 7];
            ushort u1 = ((const ushort*)&vin[(2 * i + 1) >> 3])[(2 * i + 1) & 7];
            float x0 = b2f(u0), x1 = b2f(u1);
            lo[t][j] = (short)f2b(x0 * cv - x1 * sv);
            hi[t][j] = (short)f2b(x1 * cv + x0 * sv);
        }
    }
    #pragma unroll
    for (int t = 0; t < 4; ++t) {
        *(short8*)(dst + t * 8)      = lo[t];
        *(short8*)(dst + 32 + t * 8) = hi[t];
    }
}

// ---------------- fused post-processing: rope_q | build_kf(+k-rope) | build_vt2
__global__ __launch_bounds__(256) void fuse3(
    ushort* __restrict__ q, const ushort* __restrict__ qac,
    const ushort* __restrict__ kv, ushort* __restrict__ kf,
    ushort* __restrict__ vt2, const float* __restrict__ tab) {
    __shared__ ushort Vl[64 * 136];
    const int b = blockIdx.x;
    const int tid = threadIdx.x;
    if (b < 128) {
        // rope on q_pe: 32768 (s,h) items
        int idx = b * 256 + tid;
        int s = idx >> 4, h = idx & 15;
        ushort* p = q + (size_t)s * QW + h * DQ + DN;
        rope_block(p, p, tab + s * 64);
    } else if (b < 128 + 3072) {
        // build_kf: kf[h][s][192]; parts 16..23 rope k_pe inline from qac
        int idx = (b - 128) * 256 + tid;     // SS*HH*24 items
        int part = idx % 24;
        int rest = idx / 24;
        int h = rest & 15, s = rest >> 4;
        short8 v;
        if (part < 16) {
            v = *(const short8*)(kv + (size_t)s * KVW + h * KVD + part * 8);
        } else {
            const int j8 = part - 16;            // 0..7 output 8-dim segment
            const int seg = j8 & 3;              // input 16-dim segment
            const ushort* cp = qac + (size_t)s * QAC + QLAT + KLAT + seg * 16;
            short8 a = *(const short8*)cp;
            short8 bb = *(const short8*)(cp + 8);
            const float* tb = tab + s * 64 + seg * 16;
            const bool hi = (j8 >= 4);
            #pragma unroll
            for (int jj = 0; jj < 8; ++jj) {
                float cv = tb[2 * jj], sv = tb[2 * jj + 1];
                ushort u0 = (jj < 4) ? (ushort)a[2 * jj]     : (ushort)bb[2 * jj - 8];
                ushort u1 = (jj < 4) ? (ushort)a[2 * jj + 1] : (ushort)bb[2 * jj - 7];
                float x0 = b2f(u0), x1 = b2f(u1);
                v[jj] = (short)f2b(hi ? (x1 * cv + x0 * sv) : (x0 * cv - x1 * sv));
            }
        }
        *(short8*)(kf + ((size_t)h * SS + s) * 192 + part * 8) = v;
    } else {
        // build_vt2
        const int r = b - (128 + 3072);
        const int ck = r & 31, h = r >> 5;
        const int lane = tid & 63, wv = tid >> 6;
        #pragma unroll
        for (int rr = 0; rr < 4; ++rr) {
            int n = rr * 256 + tid;
            int key = n >> 4, part = n & 15;
            short8 v = *(const short8*)(kv + (size_t)(ck * 64 + key) * KVW + h * KVD + DN + part * 8);
            *(short8*)&Vl[key * 136 + part * 8] = v;
        }
        __syncthreads();
        const int ln = lane & 15, quad = lane >> 4;
        ushort* dst = vt2 + (((size_t)h * 32 + ck) * 16) * 512;
        #pragma unroll
        for (int w = 0; w < 4; ++w) {
            int idx2 = wv * 4 + w;
            int kb2 = idx2 >> 3, nb = idx2 & 7;
            short8 v;
            #pragma unroll
            for (int j = 0; j < 8; ++j)
                ((ushort*)&v)[j] = Vl[(kb2 * 32 + quad * 8 + j) * 136 + nb * 16 + ln];
            *(short8*)(dst + (size_t)idx2 * 512 + lane * 8) = v;
        }
    }
}

// ---------------- split-K MFMA flash attention, 128 q-rows/block ------------
// v8: v7's regression (79->105us) was V-LOAD PLACEMENT, not structure: v7
// issued bv0/bv1 inside each group right before PV, exposing their full
// global-load latency twice per chunk (v6 hid bv0 under QK+softmax). Fix:
// hoist the 16 V loads to chunk top (group-invariant; v7 also loaded them
// twice). Cover: group-0 QK(24 MFMA)+softmax ~400+cyc before first use; the
// compiler's counted vmcnt before PV keeps the 6 K-prefetch loads in flight.
// Per 80 MFMA/wave: 1 barrier + 1 vmcnt + 16 V-loads (v6: 2+2+32).
// VGPR ~240 expected; spill signature = FETCH/WRITE jump (round-1 lesson).
__global__ __launch_bounds__(256, 2) void attn_mfma2(
    const ushort* __restrict__ qbf, const ushort* __restrict__ kf,
    const ushort* __restrict__ vt2, ushort* __restrict__ opart,
    float* __restrict__ ml) {
    const int seg = blockIdx.x, bq = 15 - blockIdx.y, h = blockIdx.z;
    const int ctot = 2 * bq + 2;                 // causal 64-key chunks for 128 rows
    const int c_lo = (seg * ctot) >> 2;
    const int nch = (((seg + 1) * ctot) >> 2) - c_lo;
    if (nch <= 0) return;

    __shared__ ushort Kt[2 * KTSZ];              // 2 x 24576 B
    __shared__ ushort Pt[4][16 * PT_STRIDE];     // 9216 B (reused per row-group)

    const int tid = threadIdx.x, lane = tid & 63, wl = tid >> 6;
    const int ln = lane & 15, quad = lane >> 4;
    const int qw = bq * 128 + wl * 32;           // wave's 32 rows
    const int kstart = c_lo << 6;
    const float scale = 0.07216878364870322f;    // 1/sqrt(192)

    short8 aq[2][6];
    #pragma unroll
    for (int g = 0; g < 2; ++g) {
        const ushort* qrow = qbf + (size_t)(qw + g * 16 + ln) * QW + h * DQ;
        #pragma unroll
        for (int kb = 0; kb < 6; ++kb)
            aq[g][kb] = *(const short8*)(qrow + kb * 32 + quad * 8);
    }

    const ushort* kfh = kf + (size_t)h * SS * 192;
    const ushort* vth2 = vt2 + ((size_t)h * 32 * 16) * 512 + lane * 8;

    const int key_s = tid >> 2;
    const int swp = ((tid & 3) ^ ((tid >> 3) & 3)) * 8;
    const ushort* kg = kfh + (size_t)(kstart + key_s) * 192 + swp;
    const int swq = (quad ^ ((ln >> 1) & 3)) * 8;

    f32x4 oacc[2][8];
    #pragma unroll
    for (int g = 0; g < 2; ++g)
        #pragma unroll
        for (int f = 0; f < 8; ++f) oacc[g][f] = (f32x4){0.f, 0.f, 0.f, 0.f};
    float mrow[2][4], lrow[2][4];
    #pragma unroll
    for (int g = 0; g < 2; ++g)
        #pragma unroll
        for (int r = 0; r < 4; ++r) { mrow[g][r] = -INFINITY; lrow[g][r] = 0.f; }

    // prologue: stage chunk c_lo into buffer 0
    {
        ushort* kd = Kt + tid * 8;
        #pragma unroll
        for (int i = 0; i < 6; ++i)
            async16(kg + i * 32, kd + i * 2048);
        kg += (size_t)64 * 192;
    }

    for (int c = 0; c < nch; ++c) {
        const int k0 = kstart + (c << 6);
        asm volatile("s_waitcnt vmcnt(0)" ::: "memory");
        __builtin_amdgcn_s_barrier();
        asm volatile("" ::: "memory");
        if (c + 1 < nch) {
            ushort* kd = Kt + ((c + 1) & 1) * KTSZ + tid * 8;
            #pragma unroll
            for (int i = 0; i < 6; ++i)
                async16(kg + i * 32, kd + i * 2048);
            kg += (size_t)64 * 192;
        }
        const ushort* Kcur = Kt + (c & 1) * KTSZ;
        const ushort* vfr = vth2 + (size_t)(k0 >> 6) * 16 * 512;

        // V fragments: group-invariant; issue at chunk top so their latency
        // hides under group-0 QK + softmax (the v7 bug was loading these
        // right before PV, twice)
        short8 bv0[8], bv1[8];
        #pragma unroll
        for (int nb = 0; nb < 8; ++nb) {
            bv0[nb] = *(const short8*)(vfr + (size_t)nb * 512);
            bv1[nb] = *(const short8*)(vfr + (size_t)(8 + nb) * 512);
        }

        #pragma unroll
        for (int g = 0; g < 2; ++g) {
            const int qg = qw + g * 16;           // group's first row (wave-uniform)
            if (k0 > qg + 15) continue;           // chunk fully above diagonal
            f32x4 s[4];
            #pragma unroll
            for (int ns = 0; ns < 4; ++ns) s[ns] = (f32x4){0.f, 0.f, 0.f, 0.f};
            __builtin_amdgcn_s_setprio(1);
            #pragma unroll
            for (int ns = 0; ns < 4; ++ns)
                #pragma unroll
                for (int kb = 0; kb < 6; ++kb) {
                    short8 bk = *(const short8*)&Kcur[(kb * 64 + ns * 16 + ln) * 32 + swq];
                    s[ns] = __builtin_amdgcn_mfma_f32_16x16x32_bf16(aq[g][kb], bk, s[ns], 0, 0, 0);
                }
            __builtin_amdgcn_s_setprio(0);
            float pv[4][4], rmax[4];
            #pragma unroll
            for (int ns = 0; ns < 4; ++ns)
                #pragma unroll
                for (int r = 0; r < 4; ++r)
                    pv[ns][r] = s[ns][r] * scale;
            if (k0 + 63 > qg) {                   // mask needed (wave-uniform test)
                #pragma unroll
                for (int ns = 0; ns < 4; ++ns)
                    #pragma unroll
                    for (int r = 0; r < 4; ++r)
                        if (k0 + ns * 16 + ln > qg + quad * 4 + r) pv[ns][r] = -1e30f;
            }
            #pragma unroll
            for (int r = 0; r < 4; ++r)
                rmax[r] = fmaxf(fmaxf(pv[0][r], pv[1][r]), fmaxf(pv[2][r], pv[3][r]));
            #pragma unroll
            for (int off = 8; off; off >>= 1)
                #pragma unroll
                for (int r = 0; r < 4; ++r)
                    rmax[r] = fmaxf(rmax[r], __shfl_xor(rmax[r], off));
            float alpha[4], psum[4];
            #pragma unroll
            for (int r = 0; r < 4; ++r) {
                float mnew = fmaxf(mrow[g][r], rmax[r]);
                alpha[r] = __expf(mrow[g][r] - mnew);
                mrow[g][r] = mnew;
            }
            #pragma unroll
            for (int ns = 0; ns < 4; ++ns)
                #pragma unroll
                for (int r = 0; r < 4; ++r)
                    pv[ns][r] = __expf(pv[ns][r] - mrow[g][r]);
            #pragma unroll
            for (int r = 0; r < 4; ++r)
                psum[r] = (pv[0][r] + pv[1][r]) + (pv[2][r] + pv[3][r]);
            #pragma unroll
            for (int off = 8; off; off >>= 1)
                #pragma unroll
                for (int r = 0; r < 4; ++r)
                    psum[r] += __shfl_xor(psum[r], off);
            #pragma unroll
            for (int r = 0; r < 4; ++r) lrow[g][r] = lrow[g][r] * alpha[r] + psum[r];
            #pragma unroll
            for (int f = 0; f < 8; ++f)
                #pragma unroll
                for (int r = 0; r < 4; ++r) oacc[g][f][r] *= alpha[r];
            #pragma unroll
            for (int ns = 0; ns < 4; ++ns)
                #pragma unroll
                for (int r = 0; r < 4; ++r)
                    Pt[wl][(quad * 4 + r) * PT_STRIDE + ns * 16 + ln] = f2b(pv[ns][r]);
            short8 pa0 = *(const short8*)&Pt[wl][ln * PT_STRIDE + quad * 8];
            short8 pa1 = *(const short8*)&Pt[wl][ln * PT_STRIDE + 32 + quad * 8];
            __builtin_amdgcn_s_setprio(1);
            #pragma unroll
            for (int nb = 0; nb < 8; ++nb)
                oacc[g][nb] = __builtin_amdgcn_mfma_f32_16x16x32_bf16(pa0, bv0[nb], oacc[g][nb], 0, 0, 0);
            #pragma unroll
            for (int nb = 0; nb < 8; ++nb)
                oacc[g][nb] = __builtin_amdgcn_mfma_f32_16x16x32_bf16(pa1, bv1[nb], oacc[g][nb], 0, 0, 0);
            __builtin_amdgcn_s_setprio(0);
        }
    }

    const size_t pbase = (((size_t)h * 16 + bq) * NSEG + seg) * 128;
    #pragma unroll
    for (int g = 0; g < 2; ++g) {
        #pragma unroll
        for (int nb = 0; nb < 8; ++nb)
            #pragma unroll
            for (int r = 0; r < 4; ++r) {
                const int row = wl * 32 + g * 16 + quad * 4 + r;
                opart[(pbase + row) * 128 + nb * 16 + ln] = f2b(oacc[g][nb][r]);
            }
        if (ln == 0) {
            #pragma unroll
            for (int r = 0; r < 4; ++r) {
                const int row = wl * 32 + g * 16 + quad * 4 + r;
                ml[(pbase + row) * 2]     = mrow[g][r];
                ml[(pbase + row) * 2 + 1] = lrow[g][r];
            }
        }
    }
}

// ---------------- merge partials -> obf ----------------
// seg s contributes to 128-row tile bq iff floor((s+1)*ctot/4) > floor(s*ctot/4)
// with ctot = 2*bq+2  (must match attn_mfma2's chunk-split predicate exactly)
__global__ __launch_bounds__(256) void merge_attn(
    const ushort* __restrict__ opart, const float* __restrict__ ml,
    ushort* __restrict__ obf) {
    const int q = blockIdx.x;
    const int bq = q >> 7, row = q & 127;
    const int ctot = 2 * bq + 2;
    const int t = threadIdx.x;
    #pragma unroll
    for (int pp = 0; pp < 8; ++pp) {
        int idx = pp * 256 + t;            // 0..2047 = h*128 + d
        int h = idx >> 7, d = idx & 127;
        size_t rbase = (((size_t)h * 16 + bq) * NSEG) * 128 + row;  // + s*128
        float M = -1e30f;
        #pragma unroll
        for (int s = 0; s < NSEG; ++s) {
            if ((((s + 1) * ctot) >> 2) > ((s * ctot) >> 2))
                M = fmaxf(M, ml[(rbase + (size_t)s * 128) * 2]);
        }
        float L = 0.f, acc = 0.f;
        #pragma unroll
        for (int s = 0; s < NSEG; ++s) {
            if ((((s + 1) * ctot) >> 2) > ((s * ctot) >> 2)) {
                size_t ri = rbase + (size_t)s * 128;
                float w = __expf(ml[ri * 2] - M);
                L += w * ml[ri * 2 + 1];
                acc += w * b2f(opart[ri * 128 + d]);
            }
        }
        obf[(size_t)q * OW + h * DV + d] = f2b(acc / L);
    }
}

// ---------------- launch ----------------
extern "C" void kernel_launch(void* const* d_in, const int* in_sizes, int n_in,
                              void* d_out, int out_size, void* d_ws, size_t ws_size,
                              hipStream_t stream) {
    const void* x       = d_in[0];
    const void* w_q_a   = d_in[1];
    const void* q_a_ln  = d_in[2];
    const void* w_q_b   = d_in[3];
    const void* w_kv_a  = d_in[4];
    const void* kv_a_ln = d_in[5];
    const void* w_kv_b  = d_in[6];
    const void* w_out   = d_in[7];

    char* ws = (char*)d_ws;
    int*    flag  = (int*)ws;
    ushort* qbf   = (ushort*)(ws + 256);             // S*QW
    ushort* obf   = qbf   + (size_t)SS * QW;         // S*OW
    ushort* wqat  = obf   + (size_t)SS * OW;         // QLAT*EE  } contiguous ->
    ushort* wkvat = wqat  + (size_t)QLAT * EE;       // CKVW*EE  } merged Bt[2112][EE]
    ushort* wqbt  = wkvat + (size_t)CKVW * EE;       // QW*QLAT
    ushort* wkvbt = wqbt  + (size_t)QW * QLAT;       // KVW*KLAT
    ushort* woutt = wkvbt + (size_t)KVW * KLAT;      // EE*OW
    ushort* kf    = woutt + (size_t)EE * OW;         // HH*SS*192
    ushort* vt2   = kf    + (size_t)HH * SS * 192;   // HH*SS*DV (frag-ordered)
    float*  ml    = (float*)(vt2 + (size_t)HH * SS * DV);  // HH*16*NSEG*128*2 floats
    // overlay zone (all dead before attention writes opart):
    ushort* qac   = (ushort*)(ml + (size_t)HH * 16 * NSEG * 128 * 2);  // S*QAC
    ushort* xbf   = qac   + (size_t)SS * QAC;        // S*EE
    ushort* kvbf  = xbf   + (size_t)SS * EE;         // S*KVW
    ushort* kpebf = kvbf  + (size_t)SS * KVW;        // S*DR (unused; kept for layout)
    float*  rtab  = (float*)(kpebf + (size_t)SS * DR);  // SS*32*2 floats (cos,sin)
    ushort* opart = qac;  // HH*16*NSEG*128*128 halfs <= overlay span (17.04M)

    detect_dtype<<<1, 1, 0, stream>>>((const unsigned int*)q_a_ln, flag);
    rope_tab<<<SS * 32 / 256, 256, 0, stream>>>(rtab);

    conv_x_bf<<<(SS * EE / 4 + 255) / 256, 256, 0, stream>>>(x, xbf, SS * EE, flag);
    transpose5_bf<<<dim3(64, 32, 5), 256, 0, stream>>>(
        w_q_a, w_kv_a, w_q_b, w_kv_b, w_out,
        wqat, wkvat, wqbt, wkvbt, woutt, flag);

    // qac = x @ [w_q_a | w_kv_a]  (2048 x 2112, K=2048), merged, 544 blocks
    gemm_bf64<<<dim3((QAC + 127) / 128, SS / 64), 256, 0, stream>>>(
        xbf, wqat, qac, QAC, EE, EE, EE, QAC, 1, nullptr);

    rmsnorm2_bf<<<dim3(SS, 2), 256, 0, stream>>>(qac, q_a_ln, kv_a_ln, flag);

    // qbf = qa_norm @ w_q_b  AND  kvbf = ckv_norm @ w_kv_b, one launch
    gemm_qkv<<<dim3(KVW / 128, SS / 128, 2), 256, 0, stream>>>(
        qac, wqbt, wkvbt, qbf, kvbf);

    // rope_q + build_kf(+k-rope) + build_vt2, one launch
    fuse3<<<128 + 3072 + 512, 256, 0, stream>>>(qbf, qac, kvbf, kf, vt2, rtab);

    attn_mfma2<<<dim3(NSEG, SS / 128, HH), 256, 0, stream>>>(qbf, kf, vt2, opart, ml);
    merge_attn<<<SS, 256, 0, stream>>>(opart, ml, obf);

    // out = o @ w_out (2048x2048, K=2048), 512 blocks via 64-tile
    gemm_bf64<<<dim3(EE / 128, SS / 64), 256, 0, stream>>>(
        obf, woutt, d_out, EE, OW, OW, OW, EE, 2, flag);
}

// Round 9
// 359.444 us; speedup vs baseline: 1.1106x; 1.1106x over previous
//
#include <hip/hip_runtime.h>
#include <hip/hip_bf16.h>
#include <math.h>

// Problem constants (fixed shapes)
#define SS   2048   // sequence length
#define EE   2048   // embed dim
#define HH   16     // heads
#define QLAT 1536   // q latent
#define KLAT 512    // kv latent
#define DN   128
#define DR   64
#define DV   128
#define DQ   192    // DN+DR
#define KVD  256    // DN+DV
#define CKVW 576    // KLAT+DR
#define QW   3072   // HH*DQ
#define KVW  4096   // HH*KVD
#define OW   2048   // HH*DV
#define QAC  2112   // QLAT + CKVW (merged a-proj output width)

#define NSEG 4      // key segments (flash-decoding split)
#define PT_STRIDE 72
#define KTSZ (6 * 64 * 32)   // one K-chunk in LDS (ushorts)

typedef __attribute__((ext_vector_type(8))) short short8;
typedef __attribute__((ext_vector_type(4))) float f32x4;

// ---------------- helpers ----------------
__global__ void detect_dtype(const unsigned int* __restrict__ lnw, int* flag) {
    *flag = (lnw[0] == 0x3F803F80u) ? 1 : 0;  // bf16 pair of 1.0 vs fp32 1.0
}

__device__ __forceinline__ float ld_in(const void* p, size_t i, int bf) {
    if (bf) return __bfloat162float(((const __hip_bfloat16*)p)[i]);
    return ((const float*)p)[i];
}

__device__ __forceinline__ ushort f2b(float v) {
    __hip_bfloat16 b = __float2bfloat16(v);
    return *(ushort*)&b;
}
__device__ __forceinline__ float b2f(ushort u) {
    __hip_bfloat16 b = *(__hip_bfloat16*)&u;
    return __bfloat162float(b);
}

// async global->LDS, 16 B per lane; LDS dst must be wave-uniform base + lane*16
__device__ __forceinline__ void async16(const ushort* g, ushort* l) {
    __builtin_amdgcn_global_load_lds(
        (const __attribute__((address_space(1))) void*)g,
        (__attribute__((address_space(3))) void*)l, 16, 0, 0);
}

// ---------------- fused preprocessing: rope_tab | conv_x | 5x transpose -----
// v9: one launch, exact tile counts (round-6 transpose grid was 10240 blocks
// with 64% idle early-exit). Block ranges:
//   [0,256)            rope cos/sin table (SS*32 entries)
//   [256,4352)         x -> bf16 convert (SS*EE/4 items)
//   [4352,8096)        weight transposes, flat tile index per matrix:
//                      w_q_a 24x32=768 | w_kv_a 9x32=288 | w_q_b 48x24=1152 |
//                      w_kv_b 64x8=512 | w_out 32x32=1024   (total 3744)
__global__ __launch_bounds__(256) void prep(
    const void* __restrict__ x, ushort* __restrict__ xbf, float* __restrict__ tab,
    const void* __restrict__ s0, const void* __restrict__ s1,
    const void* __restrict__ s2, const void* __restrict__ s3,
    const void* __restrict__ s4,
    ushort* __restrict__ d0, ushort* __restrict__ d1, ushort* __restrict__ d2,
    ushort* __restrict__ d3, ushort* __restrict__ d4,
    const int* __restrict__ flag) {
    __shared__ ushort tlds[64][66];
    const int b = blockIdx.x;
    const int tid = threadIdx.x;
    if (b < 256) {
        int idx = b * 256 + tid;   // SS*32
        int s = idx >> 5, i = idx & 31;
        float inv = powf(10000.0f, -(float)i / 32.0f);
        float sv, cv;
        sincosf((float)s * inv, &sv, &cv);
        tab[idx * 2]     = cv;
        tab[idx * 2 + 1] = sv;
        return;
    }
    if (b < 4352) {
        const int bf = *flag;
        int i = ((b - 256) * 256 + tid) * 4;   // exact: 4096*256*4 = SS*EE
        ushort4 u;
        u.x = f2b(ld_in(x, i + 0, bf));
        u.y = f2b(ld_in(x, i + 1, bf));
        u.z = f2b(ld_in(x, i + 2, bf));
        u.w = f2b(ld_in(x, i + 3, bf));
        *(ushort4*)(xbf + i) = u;
        return;
    }
    int t = b - 4352;
    const void* in; ushort* out; int R, C, c0, r0;
    if (t < 768)       {          in = s0; out = d0; R = EE;   C = QLAT; c0 = (t % 24) << 6; r0 = (t / 24) << 6; }
    else if (t < 1056) { t -= 768;  in = s1; out = d1; R = EE;   C = CKVW; c0 = (t % 9)  << 6; r0 = (t / 9)  << 6; }
    else if (t < 2208) { t -= 1056; in = s2; out = d2; R = QLAT; C = QW;   c0 = (t % 48) << 6; r0 = (t / 48) << 6; }
    else if (t < 2720) { t -= 2208; in = s3; out = d3; R = KLAT; C = KVW;  c0 = (t % 64) << 6; r0 = (t / 64) << 6; }
    else               { t -= 2720; in = s4; out = d4; R = OW;   C = EE;   c0 = (t % 32) << 6; r0 = (t / 32) << 6; }
    const int bf = *flag;
    const int lane = tid & 63, grp = tid >> 6;
    #pragma unroll
    for (int p = 0; p < 16; ++p) {
        int r = p * 4 + grp;
        tlds[lane][r] = f2b(ld_in(in, (size_t)(r0 + r) * C + c0 + lane, bf));
    }
    __syncthreads();
    const int ro = (tid & 31) * 2, co = tid >> 5;
    #pragma unroll
    for (int p = 0; p < 8; ++p) {
        int c = p * 8 + co;
        ushort2 u = *(const ushort2*)&tlds[c][ro];
        *(ushort2*)&out[(size_t)(c0 + c) * R + r0 + ro] = u;
    }
}

// ---------------- bf16 MFMA GEMM 128x128 body, BK=64 double-buffered --------
__device__ __forceinline__ void gemm128_body(
    const ushort* __restrict__ A, const ushort* __restrict__ Bt,
    void* __restrict__ C, int N, int K, int lda, int ldb, int ldc,
    int cbf, int bm, int bn, ushort* As, ushort* Bs) {
    const int tid = threadIdx.x;
    const int lane = tid & 63, wv = tid >> 6;
    const int wm = (wv & 1) * 64, wn = (wv >> 1) * 64;
    const int ln = lane & 15, quad = lane >> 4;

    f32x4 acc[4][4];
    #pragma unroll
    for (int i = 0; i < 4; ++i)
        #pragma unroll
        for (int j = 0; j < 4; ++j) acc[i][j] = (f32x4){0.f, 0.f, 0.f, 0.f};

    const int srow = tid >> 3;                       // 0..31
    const int spart = ((tid & 7) ^ ((tid >> 3) & 7)) * 8;  // swizzled src 16B part
    const ushort* Ag0 = A + (size_t)(bm + srow) * lda + spart;
    const ushort* Ag1 = Ag0 + (size_t)32 * lda;
    const ushort* Ag2 = Ag0 + (size_t)64 * lda;
    const ushort* Ag3 = Ag0 + (size_t)96 * lda;
    const int br0 = (bn + srow)      < N ? (bn + srow)      : (N - 1);
    const int br1 = (bn + 32 + srow) < N ? (bn + 32 + srow) : (N - 1);
    const int br2 = (bn + 64 + srow) < N ? (bn + 64 + srow) : (N - 1);
    const int br3 = (bn + 96 + srow) < N ? (bn + 96 + srow) : (N - 1);
    const ushort* Bg0 = Bt + (size_t)br0 * ldb + spart;
    const ushort* Bg1 = Bt + (size_t)br1 * ldb + spart;
    const ushort* Bg2 = Bt + (size_t)br2 * ldb + spart;
    const ushort* Bg3 = Bt + (size_t)br3 * ldb + spart;
    const int nsteps = K >> 6;

    // prologue: stage step 0 into buffer 0
    {
        ushort* as = As + tid * 8;
        ushort* bs = Bs + tid * 8;
        async16(Ag0, as);          async16(Ag1, as + 2048);
        async16(Ag2, as + 4096);   async16(Ag3, as + 6144);
        async16(Bg0, bs);          async16(Bg1, bs + 2048);
        async16(Bg2, bs + 4096);   async16(Bg3, bs + 6144);
    }

    int cb = 0;
    for (int c = 0; c < nsteps; ++c) {
        asm volatile("s_waitcnt vmcnt(0)" ::: "memory");
        __builtin_amdgcn_s_barrier();
        asm volatile("" ::: "memory");
        if (c + 1 < nsteps) {
            const int k1 = (c + 1) << 6;
            ushort* as = As + (cb ^ 1) * 8192 + tid * 8;
            ushort* bs = Bs + (cb ^ 1) * 8192 + tid * 8;
            async16(Ag0 + k1, as);          async16(Ag1 + k1, as + 2048);
            async16(Ag2 + k1, as + 4096);   async16(Ag3 + k1, as + 6144);
            async16(Bg0 + k1, bs);          async16(Bg1 + k1, bs + 2048);
            async16(Bg2 + k1, bs + 4096);   async16(Bg3 + k1, bs + 6144);
        }
        const ushort* Ac = As + cb * 8192;
        const ushort* Bc = Bs + cb * 8192;
        #pragma unroll
        for (int ks = 0; ks < 2; ++ks) {
            const int sw = ((ks * 4 + quad) ^ (ln & 7)) * 8;
            short8 af[4], bfr[4];
            #pragma unroll
            for (int t = 0; t < 4; ++t) {
                af[t]  = *(const short8*)&Ac[(wm + t * 16 + ln) * 64 + sw];
                bfr[t] = *(const short8*)&Bc[(wn + t * 16 + ln) * 64 + sw];
            }
            __builtin_amdgcn_s_setprio(1);
            #pragma unroll
            for (int i = 0; i < 4; ++i)
                #pragma unroll
                for (int j = 0; j < 4; ++j)
                    acc[i][j] = __builtin_amdgcn_mfma_f32_16x16x32_bf16(af[i], bfr[j], acc[i][j], 0, 0, 0);
            __builtin_amdgcn_s_setprio(0);
        }
        cb ^= 1;
    }

    #pragma unroll
    for (int i = 0; i < 4; ++i) {
        #pragma unroll
        for (int r = 0; r < 4; ++r) {
            const int m = bm + wm + i * 16 + quad * 4 + r;
            #pragma unroll
            for (int j = 0; j < 4; ++j) {
                const int n = bn + wn + j * 16 + ln;
                if (n < N) {
                    if (cbf) ((ushort*)C)[(size_t)m * ldc + n] = f2b(acc[i][j][r]);
                    else     ((float*)C)[(size_t)m * ldc + n] = acc[i][j][r];
                }
            }
        }
    }
}

// merged q_b + kv_b GEMMs: z selects; 896 useful blocks run concurrently
__global__ __launch_bounds__(256) void gemm_qkv(
    const ushort* __restrict__ qac, const ushort* __restrict__ wqbt,
    const ushort* __restrict__ wkvbt, ushort* __restrict__ qbf_,
    ushort* __restrict__ kvbf_) {
    __shared__ ushort As[2 * 8192];
    __shared__ ushort Bs[2 * 8192];
    if (blockIdx.z == 0) {
        if (blockIdx.x >= QW / 128) return;
        gemm128_body(qac, wqbt, qbf_, QW, QLAT, QAC, QLAT, QW, 1,
                     blockIdx.y * 128, blockIdx.x * 128, As, Bs);
    } else {
        gemm128_body(qac + QLAT, wkvbt, kvbf_, KVW, KLAT, QAC, KLAT, KVW, 1,
                     blockIdx.y * 128, blockIdx.x * 128, As, Bs);
    }
}

// ---------------- bf16 MFMA GEMM 64x128, BK=64 double-buffered --------------
__global__ __launch_bounds__(256) void gemm_bf64(
    const ushort* __restrict__ A, const ushort* __restrict__ Bt,
    void* __restrict__ C, int N, int K, int lda, int ldb, int ldc,
    int cmode, const int* __restrict__ cflag) {
    __shared__ ushort As[2 * 4096];
    __shared__ ushort Bs[2 * 8192];
    const int tid = threadIdx.x;
    const int bm = blockIdx.y * 64, bn = blockIdx.x * 128;
    const int lane = tid & 63, wv = tid >> 6;
    const int wm = (wv & 1) * 32, wn = (wv >> 1) * 64;
    const int ln = lane & 15, quad = lane >> 4;

    int cbf = cmode;
    if (cmode == 2) cbf = *(volatile const int*)cflag;  // before staging loads

    f32x4 acc[2][4];
    #pragma unroll
    for (int i = 0; i < 2; ++i)
        #pragma unroll
        for (int j = 0; j < 4; ++j) acc[i][j] = (f32x4){0.f, 0.f, 0.f, 0.f};

    const int srow = tid >> 3;
    const int spart = ((tid & 7) ^ ((tid >> 3) & 7)) * 8;
    const ushort* Ag0 = A + (size_t)(bm + srow) * lda + spart;
    const ushort* Ag1 = Ag0 + (size_t)32 * lda;
    const int br0 = (bn + srow)      < N ? (bn + srow)      : (N - 1);
    const int br1 = (bn + 32 + srow) < N ? (bn + 32 + srow) : (N - 1);
    const int br2 = (bn + 64 + srow) < N ? (bn + 64 + srow) : (N - 1);
    const int br3 = (bn + 96 + srow) < N ? (bn + 96 + srow) : (N - 1);
    const ushort* Bg0 = Bt + (size_t)br0 * ldb + spart;
    const ushort* Bg1 = Bt + (size_t)br1 * ldb + spart;
    const ushort* Bg2 = Bt + (size_t)br2 * ldb + spart;
    const ushort* Bg3 = Bt + (size_t)br3 * ldb + spart;
    const int nsteps = K >> 6;

    {
        ushort* as = As + tid * 8;
        ushort* bs = Bs + tid * 8;
        async16(Ag0, as);          async16(Ag1, as + 2048);
        async16(Bg0, bs);          async16(Bg1, bs + 2048);
        async16(Bg2, bs + 4096);   async16(Bg3, bs + 6144);
    }

    int cb = 0;
    for (int c = 0; c < nsteps; ++c) {
        asm volatile("s_waitcnt vmcnt(0)" ::: "memory");
        __builtin_amdgcn_s_barrier();
        asm volatile("" ::: "memory");
        if (c + 1 < nsteps) {
            const int k1 = (c + 1) << 6;
            ushort* as = As + (cb ^ 1) * 4096 + tid * 8;
            ushort* bs = Bs + (cb ^ 1) * 8192 + tid * 8;
            async16(Ag0 + k1, as);          async16(Ag1 + k1, as + 2048);
            async16(Bg0 + k1, bs);          async16(Bg1 + k1, bs + 2048);
            async16(Bg2 + k1, bs + 4096);   async16(Bg3 + k1, bs + 6144);
        }
        const ushort* Ac = As + cb * 4096;
        const ushort* Bc = Bs + cb * 8192;
        #pragma unroll
        for (int ks = 0; ks < 2; ++ks) {
            const int sw = ((ks * 4 + quad) ^ (ln & 7)) * 8;
            short8 af[2], bfr[4];
            #pragma unroll
            for (int t = 0; t < 2; ++t)
                af[t] = *(const short8*)&Ac[(wm + t * 16 + ln) * 64 + sw];
            #pragma unroll
            for (int t = 0; t < 4; ++t)
                bfr[t] = *(const short8*)&Bc[(wn + t * 16 + ln) * 64 + sw];
            __builtin_amdgcn_s_setprio(1);
            #pragma unroll
            for (int i = 0; i < 2; ++i)
                #pragma unroll
                for (int j = 0; j < 4; ++j)
                    acc[i][j] = __builtin_amdgcn_mfma_f32_16x16x32_bf16(af[i], bfr[j], acc[i][j], 0, 0, 0);
            __builtin_amdgcn_s_setprio(0);
        }
        cb ^= 1;
    }

    #pragma unroll
    for (int i = 0; i < 2; ++i) {
        #pragma unroll
        for (int r = 0; r < 4; ++r) {
            const int m = bm + wm + i * 16 + quad * 4 + r;
            #pragma unroll
            for (int j = 0; j < 4; ++j) {
                const int n = bn + wn + j * 16 + ln;
                if (n < N) {
                    if (cbf) ((ushort*)C)[(size_t)m * ldc + n] = f2b(acc[i][j][r]);
                    else     ((float*)C)[(size_t)m * ldc + n] = acc[i][j][r];
                }
            }
        }
    }
}

// ---------------- RMSNorm bf16 in-place (fp32 math), both norms fused ------
__global__ __launch_bounds__(256) void rmsnorm2_bf(
    ushort* __restrict__ x, const void* __restrict__ wq,
    const void* __restrict__ wkv, const int* wflag) {
    const int wbf = *wflag;
    const int which = blockIdx.y;
    const int cols = which ? KLAT : QLAT;
    const void* w = which ? wkv : wq;
    ushort* p = x + (size_t)blockIdx.x * QAC + (which ? QLAT : 0);
    float ss = 0.f;
    for (int i = threadIdx.x; i < cols; i += 256) { float v = b2f(p[i]); ss += v * v; }
    #pragma unroll
    for (int off = 32; off; off >>= 1) ss += __shfl_xor(ss, off);
    __shared__ float red[4];
    const int wid = threadIdx.x >> 6, lane = threadIdx.x & 63;
    if (lane == 0) red[wid] = ss;
    __syncthreads();
    const float tot = red[0] + red[1] + red[2] + red[3];
    const float scale = rsqrtf(tot / (float)cols + 1e-6f);
    for (int i = threadIdx.x; i < cols; i += 256)
        p[i] = f2b(b2f(p[i]) * scale * ld_in(w, i, wbf));
}

__device__ __forceinline__ void rope_block(
    const ushort* __restrict__ src, ushort* __restrict__ dst,
    const float* __restrict__ tb) {
    short8 vin[8];
    #pragma unroll
    for (int t = 0; t < 8; ++t) vin[t] = *(const short8*)(src + t * 8);
    short8 lo[4], hi[4];
    #pragma unroll
    for (int t = 0; t < 4; ++t) {
        #pragma unroll
        for (int j = 0; j < 8; ++j) {
            const int i = t * 8 + j;
            float cv = tb[2 * i], sv = tb[2 * i + 1];
            ushort u0 = ((const ushort*)&vin[(2 * i) >> 3])[(2 * i) & 7];
            ushort u1 = ((const ushort*)&vin[(2 * i + 1) >> 3])[(2 * i + 1) & 7];
            float x0 = b2f(u0), x1 = b2f(u1);
            lo[t][j] = (short)f2b(x0 * cv - x1 * sv);
            hi[t][j] = (short)f2b(x1 * cv + x0 * sv);
        }
    }
    #pragma unroll
    for (int t = 0; t < 4; ++t) {
        *(short8*)(dst + t * 8)      = lo[t];
        *(short8*)(dst + 32 + t * 8) = hi[t];
    }
}

// ---------------- fused post-processing: rope_q | build_kf(+k-rope) | build_vt2
__global__ __launch_bounds__(256) void fuse3(
    ushort* __restrict__ q, const ushort* __restrict__ qac,
    const ushort* __restrict__ kv, ushort* __restrict__ kf,
    ushort* __restrict__ vt2, const float* __restrict__ tab) {
    __shared__ ushort Vl[64 * 136];
    const int b = blockIdx.x;
    const int tid = threadIdx.x;
    if (b < 128) {
        // rope on q_pe: 32768 (s,h) items
        int idx = b * 256 + tid;
        int s = idx >> 4, h = idx & 15;
        ushort* p = q + (size_t)s * QW + h * DQ + DN;
        rope_block(p, p, tab + s * 64);
    } else if (b < 128 + 3072) {
        // build_kf: kf[h][s][192]; parts 16..23 rope k_pe inline from qac
        int idx = (b - 128) * 256 + tid;     // SS*HH*24 items
        int part = idx % 24;
        int rest = idx / 24;
        int h = rest & 15, s = rest >> 4;
        short8 v;
        if (part < 16) {
            v = *(const short8*)(kv + (size_t)s * KVW + h * KVD + part * 8);
        } else {
            const int j8 = part - 16;            // 0..7 output 8-dim segment
            const int seg = j8 & 3;              // input 16-dim segment
            const ushort* cp = qac + (size_t)s * QAC + QLAT + KLAT + seg * 16;
            short8 a = *(const short8*)cp;
            short8 bb = *(const short8*)(cp + 8);
            const float* tb = tab + s * 64 + seg * 16;
            const bool hi = (j8 >= 4);
            #pragma unroll
            for (int jj = 0; jj < 8; ++jj) {
                float cv = tb[2 * jj], sv = tb[2 * jj + 1];
                ushort u0 = (jj < 4) ? (ushort)a[2 * jj]     : (ushort)bb[2 * jj - 8];
                ushort u1 = (jj < 4) ? (ushort)a[2 * jj + 1] : (ushort)bb[2 * jj - 7];
                float x0 = b2f(u0), x1 = b2f(u1);
                v[jj] = (short)f2b(hi ? (x1 * cv + x0 * sv) : (x0 * cv - x1 * sv));
            }
        }
        *(short8*)(kf + ((size_t)h * SS + s) * 192 + part * 8) = v;
    } else {
        // build_vt2
        const int r = b - (128 + 3072);
        const int ck = r & 31, h = r >> 5;
        const int lane = tid & 63, wv = tid >> 6;
        #pragma unroll
        for (int rr = 0; rr < 4; ++rr) {
            int n = rr * 256 + tid;
            int key = n >> 4, part = n & 15;
            short8 v = *(const short8*)(kv + (size_t)(ck * 64 + key) * KVW + h * KVD + DN + part * 8);
            *(short8*)&Vl[key * 136 + part * 8] = v;
        }
        __syncthreads();
        const int ln = lane & 15, quad = lane >> 4;
        ushort* dst = vt2 + (((size_t)h * 32 + ck) * 16) * 512;
        #pragma unroll
        for (int w = 0; w < 4; ++w) {
            int idx2 = wv * 4 + w;
            int kb2 = idx2 >> 3, nb = idx2 & 7;
            short8 v;
            #pragma unroll
            for (int j = 0; j < 8; ++j)
                ((ushort*)&v)[j] = Vl[(kb2 * 32 + quad * 8 + j) * 136 + nb * 16 + ln];
            *(short8*)(dst + (size_t)idx2 * 512 + lane * 8) = v;
        }
    }
}

// ---------------- split-K MFMA flash attention (v6 64-row, proven 79us) -----
// v9: REVERT from the 128-row structure. v7/v8 evidence: its ~240-VGPR live
// demand vs the allocator's 128-VGPR choice meant the scheduler re-sank the
// V loads / spilled small state, eating the fixed-cost savings (102-105us vs
// 79). The 64-row form's VGPR=92 is why its load scheduling works.
__global__ __launch_bounds__(256, 2) void attn_mfma2(
    const ushort* __restrict__ qbf, const ushort* __restrict__ kf,
    const ushort* __restrict__ vt2, ushort* __restrict__ opart,
    float* __restrict__ ml) {
    const int seg = blockIdx.x, bq = 31 - blockIdx.y, h = blockIdx.z;
    const int ctot = bq + 1;
    const int c_lo = (seg * ctot) >> 2;
    const int nch = (((seg + 1) * ctot) >> 2) - c_lo;
    if (nch <= 0) return;

    __shared__ ushort Kt[2 * KTSZ];              // 2 x 24576 B
    __shared__ ushort Pt[4][16 * PT_STRIDE];     // 9216 B

    const int tid = threadIdx.x, lane = tid & 63, wl = tid >> 6;
    const int ln = lane & 15, quad = lane >> 4;
    const int qw = bq * 64 + wl * 16;
    const int kstart = c_lo << 6;
    const float scale = 0.07216878364870322f;  // 1/sqrt(192)

    short8 aq[6];
    const ushort* qrow = qbf + (size_t)(qw + ln) * QW + h * DQ;
    #pragma unroll
    for (int kb = 0; kb < 6; ++kb)
        aq[kb] = *(const short8*)(qrow + kb * 32 + quad * 8);

    const ushort* kfh = kf + (size_t)h * SS * 192;
    const ushort* vth2 = vt2 + ((size_t)h * 32 * 16) * 512 + lane * 8;

    const int key_s = tid >> 2;
    const int swp = ((tid & 3) ^ ((tid >> 3) & 3)) * 8;
    const ushort* kg = kfh + (size_t)(kstart + key_s) * 192 + swp;
    const int swq = (quad ^ ((ln >> 1) & 3)) * 8;

    f32x4 oacc[8];
    #pragma unroll
    for (int f = 0; f < 8; ++f) oacc[f] = (f32x4){0.f, 0.f, 0.f, 0.f};
    float mrow[4] = {-INFINITY, -INFINITY, -INFINITY, -INFINITY};
    float lrow[4] = {0.f, 0.f, 0.f, 0.f};

    {
        ushort* kd = Kt + tid * 8;
        #pragma unroll
        for (int i = 0; i < 6; ++i)
            async16(kg + i * 32, kd + i * 2048);
        kg += (size_t)64 * 192;
    }

    for (int c = 0; c < nch; ++c) {
        const int k0 = kstart + (c << 6);
        asm volatile("s_waitcnt vmcnt(0)" ::: "memory");
        __builtin_amdgcn_s_barrier();
        asm volatile("" ::: "memory");
        if (c + 1 < nch) {
            ushort* kd = Kt + ((c + 1) & 1) * KTSZ + tid * 8;
            #pragma unroll
            for (int i = 0; i < 6; ++i)
                async16(kg + i * 32, kd + i * 2048);
            kg += (size_t)64 * 192;
        }
        const ushort* Kcur = Kt + (c & 1) * KTSZ;

        const ushort* vfr = vth2 + (size_t)(k0 >> 6) * 16 * 512;
        short8 bv0[8];
        #pragma unroll
        for (int nb = 0; nb < 8; ++nb)
            bv0[nb] = *(const short8*)(vfr + (size_t)nb * 512);
        f32x4 s[4];
        #pragma unroll
        for (int ns = 0; ns < 4; ++ns) s[ns] = (f32x4){0.f, 0.f, 0.f, 0.f};
        __builtin_amdgcn_s_setprio(1);
        #pragma unroll
        for (int ns = 0; ns < 4; ++ns)
            #pragma unroll
            for (int kb = 0; kb < 6; ++kb) {
                short8 bk = *(const short8*)&Kcur[(kb * 64 + ns * 16 + ln) * 32 + swq];
                s[ns] = __builtin_amdgcn_mfma_f32_16x16x32_bf16(aq[kb], bk, s[ns], 0, 0, 0);
            }
        __builtin_amdgcn_s_setprio(0);
        float pv[4][4], rmax[4];
        #pragma unroll
        for (int r = 0; r < 4; ++r) rmax[r] = -1e30f;
        #pragma unroll
        for (int ns = 0; ns < 4; ++ns)
            #pragma unroll
            for (int r = 0; r < 4; ++r) {
                int key = k0 + ns * 16 + ln;
                int qr = qw + quad * 4 + r;
                float v = s[ns][r] * scale;
                if (key > qr) v = -1e30f;
                pv[ns][r] = v;
                rmax[r] = fmaxf(rmax[r], v);
            }
        #pragma unroll
        for (int off = 8; off; off >>= 1)
            #pragma unroll
            for (int r = 0; r < 4; ++r)
                rmax[r] = fmaxf(rmax[r], __shfl_xor(rmax[r], off));
        float alpha[4], psum[4];
        #pragma unroll
        for (int r = 0; r < 4; ++r) {
            float mnew = fmaxf(mrow[r], rmax[r]);
            alpha[r] = __expf(mrow[r] - mnew);
            mrow[r] = mnew;
        }
        #pragma unroll
        for (int ns = 0; ns < 4; ++ns)
            #pragma unroll
            for (int r = 0; r < 4; ++r)
                pv[ns][r] = __expf(pv[ns][r] - mrow[r]);
        #pragma unroll
        for (int r = 0; r < 4; ++r)
            psum[r] = (pv[0][r] + pv[1][r]) + (pv[2][r] + pv[3][r]);
        #pragma unroll
        for (int off = 8; off; off >>= 1)
            #pragma unroll
            for (int r = 0; r < 4; ++r)
                psum[r] += __shfl_xor(psum[r], off);
        #pragma unroll
        for (int r = 0; r < 4; ++r) lrow[r] = lrow[r] * alpha[r] + psum[r];
        #pragma unroll
        for (int f = 0; f < 8; ++f)
            #pragma unroll
            for (int r = 0; r < 4; ++r) oacc[f][r] *= alpha[r];
        #pragma unroll
        for (int ns = 0; ns < 4; ++ns)
            #pragma unroll
            for (int r = 0; r < 4; ++r)
                Pt[wl][(quad * 4 + r) * PT_STRIDE + ns * 16 + ln] = f2b(pv[ns][r]);
        short8 bv1[8];
        #pragma unroll
        for (int nb = 0; nb < 8; ++nb)
            bv1[nb] = *(const short8*)(vfr + (size_t)(8 + nb) * 512);
        short8 pa0 = *(const short8*)&Pt[wl][ln * PT_STRIDE + quad * 8];
        short8 pa1 = *(const short8*)&Pt[wl][ln * PT_STRIDE + 32 + quad * 8];
        __builtin_amdgcn_s_setprio(1);
        #pragma unroll
        for (int nb = 0; nb < 8; ++nb)
            oacc[nb] = __builtin_amdgcn_mfma_f32_16x16x32_bf16(pa0, bv0[nb], oacc[nb], 0, 0, 0);
        #pragma unroll
        for (int nb = 0; nb < 8; ++nb)
            oacc[nb] = __builtin_amdgcn_mfma_f32_16x16x32_bf16(pa1, bv1[nb], oacc[nb], 0, 0, 0);
        __builtin_amdgcn_s_setprio(0);
    }

    const size_t pbase = (((size_t)h * 32 + bq) * NSEG + seg) * 64;
    #pragma unroll
    for (int nb = 0; nb < 8; ++nb)
        #pragma unroll
        for (int r = 0; r < 4; ++r)
            opart[(pbase + wl * 16 + quad * 4 + r) * 128 + nb * 16 + ln] = f2b(oacc[nb][r]);
    if (ln == 0) {
        #pragma unroll
        for (int r = 0; r < 4; ++r) {
            ml[(pbase + wl * 16 + quad * 4 + r) * 2]     = mrow[r];
            ml[(pbase + wl * 16 + quad * 4 + r) * 2 + 1] = lrow[r];
        }
    }
}

// ---------------- merge partials -> obf (v6 64-row form) ----------------
// seg s contributes to row-tile bq iff floor((s+1)*ctot/4) > floor(s*ctot/4)
// with ctot = bq+1  (must match attn_mfma2's chunk-split predicate exactly)
__global__ __launch_bounds__(256) void merge_attn(
    const ushort* __restrict__ opart, const float* __restrict__ ml,
    ushort* __restrict__ obf) {
    const int q = blockIdx.x;
    const int bq = q >> 6, row = q & 63;
    const int ctot = bq + 1;
    const int t = threadIdx.x;
    #pragma unroll
    for (int pp = 0; pp < 8; ++pp) {
        int idx = pp * 256 + t;            // 0..2047 = h*128 + d
        int h = idx >> 7, d = idx & 127;
        size_t rbase = (((size_t)h * 32 + bq) * NSEG) * 64 + row;  // + s*64
        float M = -1e30f;
        #pragma unroll
        for (int s = 0; s < NSEG; ++s) {
            if ((((s + 1) * ctot) >> 2) > ((s * ctot) >> 2))
                M = fmaxf(M, ml[(rbase + (size_t)s * 64) * 2]);
        }
        float L = 0.f, acc = 0.f;
        #pragma unroll
        for (int s = 0; s < NSEG; ++s) {
            if ((((s + 1) * ctot) >> 2) > ((s * ctot) >> 2)) {
                size_t ri = rbase + (size_t)s * 64;
                float w = __expf(ml[ri * 2] - M);
                L += w * ml[ri * 2 + 1];
                acc += w * b2f(opart[ri * 128 + d]);
            }
        }
        obf[(size_t)q * OW + h * DV + d] = f2b(acc / L);
    }
}

// ---------------- launch ----------------
extern "C" void kernel_launch(void* const* d_in, const int* in_sizes, int n_in,
                              void* d_out, int out_size, void* d_ws, size_t ws_size,
                              hipStream_t stream) {
    const void* x       = d_in[0];
    const void* w_q_a   = d_in[1];
    const void* q_a_ln  = d_in[2];
    const void* w_q_b   = d_in[3];
    const void* w_kv_a  = d_in[4];
    const void* kv_a_ln = d_in[5];
    const void* w_kv_b  = d_in[6];
    const void* w_out   = d_in[7];

    char* ws = (char*)d_ws;
    int*    flag  = (int*)ws;
    ushort* qbf   = (ushort*)(ws + 256);             // S*QW
    ushort* obf   = qbf   + (size_t)SS * QW;         // S*OW
    ushort* wqat  = obf   + (size_t)SS * OW;         // QLAT*EE  } contiguous ->
    ushort* wkvat = wqat  + (size_t)QLAT * EE;       // CKVW*EE  } merged Bt[2112][EE]
    ushort* wqbt  = wkvat + (size_t)CKVW * EE;       // QW*QLAT
    ushort* wkvbt = wqbt  + (size_t)QW * QLAT;       // KVW*KLAT
    ushort* woutt = wkvbt + (size_t)KVW * KLAT;      // EE*OW
    ushort* kf    = woutt + (size_t)EE * OW;         // HH*SS*192
    ushort* vt2   = kf    + (size_t)HH * SS * 192;   // HH*SS*DV (frag-ordered)
    float*  ml    = (float*)(vt2 + (size_t)HH * SS * DV);  // HH*32*NSEG*64*2 floats
    // overlay zone (all dead before attention writes opart):
    ushort* qac   = (ushort*)(ml + (size_t)HH * 32 * NSEG * 64 * 2);  // S*QAC
    ushort* xbf   = qac   + (size_t)SS * QAC;        // S*EE
    ushort* kvbf  = xbf   + (size_t)SS * EE;         // S*KVW
    ushort* kpebf = kvbf  + (size_t)SS * KVW;        // S*DR (unused; kept for layout)
    float*  rtab  = (float*)(kpebf + (size_t)SS * DR);  // SS*32*2 floats (cos,sin)
    ushort* opart = qac;  // HH*32*NSEG*64*128 halfs <= overlay span (17.04M)

    detect_dtype<<<1, 1, 0, stream>>>((const unsigned int*)q_a_ln, flag);

    // rope table + x convert + all 5 weight transposes, one launch
    prep<<<8096, 256, 0, stream>>>(
        x, xbf, rtab,
        w_q_a, w_kv_a, w_q_b, w_kv_b, w_out,
        wqat, wkvat, wqbt, wkvbt, woutt, flag);

    // qac = x @ [w_q_a | w_kv_a]  (2048 x 2112, K=2048), merged, 544 blocks
    gemm_bf64<<<dim3((QAC + 127) / 128, SS / 64), 256, 0, stream>>>(
        xbf, wqat, qac, QAC, EE, EE, EE, QAC, 1, nullptr);

    rmsnorm2_bf<<<dim3(SS, 2), 256, 0, stream>>>(qac, q_a_ln, kv_a_ln, flag);

    // qbf = qa_norm @ w_q_b  AND  kvbf = ckv_norm @ w_kv_b, one launch
    gemm_qkv<<<dim3(KVW / 128, SS / 128, 2), 256, 0, stream>>>(
        qac, wqbt, wkvbt, qbf, kvbf);

    // rope_q + build_kf(+k-rope) + build_vt2, one launch
    fuse3<<<128 + 3072 + 512, 256, 0, stream>>>(qbf, qac, kvbf, kf, vt2, rtab);

    attn_mfma2<<<dim3(NSEG, SS / 64, HH), 256, 0, stream>>>(qbf, kf, vt2, opart, ml);
    merge_attn<<<SS, 256, 0, stream>>>(opart, ml, obf);

    // out = o @ w_out (2048x2048, K=2048), 512 blocks via 64-tile
    gemm_bf64<<<dim3(EE / 128, SS / 64), 256, 0, stream>>>(
        obf, woutt, d_out, EE, OW, OW, OW, EE, 2, flag);
}